// Round 16
// baseline (36.127 us; speedup 1.0000x reference)
//
#include <hip/hip_runtime.h>

// ExplicitLiePE via MFMA: y[b,s] = expm(A) @ x[b,s], A = sum_k r_k * 0.5*(L_k - L_k^T).
//
// Lineage: r13/r15 (best: 29.6us): 16-token groups, row-split waves, inline
// A-fragment build, dbuf LDS b-exchange, 1 barrier/step, M margin +12.
// Wall model (quantitatively verified r15): wall = maxM(~36) x ring(~1700cy);
// ring = issue(~350cy) + ds round-trip + barrier convergence, 2 waves/SIMD.
// Closed levers: r7/r8 duplication, r9 fat blocks, r10 no-exchange, r11
// cond-renorm, r12 double-step Z^2, r14 MFMA de-chaining (all regressed).
//
// Round-16: BARRIER-GROUP WIDTH 4 -> 2. Blocks of 128 threads: 2 waves, wave w
// owns rows [32w, 32w+32) (m2 tiles {2w, 2w+1}); 512 blocks -> 4 blocks/CU,
// still 2 waves/SIMD and cross-block SIMD interleave unchanged. The per-step
// barrier now waits on max-of-2 wave phases instead of max-of-4 (the skew is
// random issue-contention with the co-resident block). Per-wave issue doubles
// (36 MFMA, 8-value pack) but issue is ~20% of the ring and overlaps the other
// block. Per-token arithmetic bit-identical -> absmax exactly 0.015625.
// Spill guard: amdgpu_waves_per_eu(1,2) (demand ~180 VGPR; r7 lesson).
//
// Math: G_k = (L_k - L_k^T).B, t[:,c] = sum_k (r_k[c]/rho_c) G_k[:,c]
// via v_mfma_f32_16x16x32_f16 with f16 hi/lo split of both L' and b
// (Lhi.bhi + Lhi.blo + Llo.bhi; dropped term ~2^-24). Miller backward
// recurrence generates Bessel coeffs on the fly; per-step renorm
// s = jc>1 ? rcp(jc) : 1 (result scale-invariant). Seed at m==ms, gate m<=M.
//
// Layouts:
//  - C/D: reg r of lane l, tile m2 = D[16*m2 + (l>>4)*4 + r][l&15] (m89/m91).
//  - A/B k-slot bijection k = 8*(l>>4)+j within each K=32 tile.
//  - staging: stage[buf][hi/lo][token c][dword]; token stride 36 dwords.

typedef _Float16 half8 __attribute__((ext_vector_type(8)));
typedef __fp16 fp16x2 __attribute__((ext_vector_type(2)));
typedef float float4t __attribute__((ext_vector_type(4)));

union H2U { fp16x2 h; unsigned u; };

__device__ __forceinline__ unsigned pkrtz2(float a, float b) {
    H2U v; v.h = __builtin_amdgcn_cvt_pkrtz(a, b); return v.u;
}
__device__ __forceinline__ float h2lo(unsigned u) { H2U v; v.u = u; return (float)v.h[0]; }
__device__ __forceinline__ float h2hi(unsigned u) { H2U v; v.u = u; return (float)v.h[1]; }

// ---------------- main kernel: 2 waves per block, 16 tokens per block --------

#define PSTR 36   // token stride in dwords (b128-aligned reads)

// stage own b1 slices (2 tiles, hi/lo f16), sync, load full-K B frags, flip.
#define STAGE_AND_LOAD_B()                                                       \
  {                                                                              \
    _Pragma("unroll")                                                            \
    for (int t2 = 0; t2 < 2; ++t2) {                                             \
      unsigned h0 = pkrtz2(b1[4*t2+0], b1[4*t2+1]);                              \
      unsigned h1 = pkrtz2(b1[4*t2+2], b1[4*t2+3]);                              \
      unsigned l0 = pkrtz2(b1[4*t2+0] - h2lo(h0), b1[4*t2+1] - h2hi(h0));        \
      unsigned l1 = pkrtz2(b1[4*t2+2] - h2lo(h1), b1[4*t2+3] - h2hi(h1));        \
      const int di = 8 * (2 * w + t2) + 2 * g;                                   \
      *(uint2*)&stage[buf][0][c][di] = make_uint2(h0, h1);                       \
      *(uint2*)&stage[buf][1][c][di] = make_uint2(l0, l1);                       \
    }                                                                            \
    __syncthreads();                                                             \
    _Pragma("unroll")                                                            \
    for (int kt = 0; kt < 2; ++kt) {                                             \
      Bh[kt] = *(const half8*)&stage[buf][0][c][16 * kt + 4 * g];                \
      Bl[kt] = *(const half8*)&stage[buf][1][c][16 * kt + 4 * g];                \
    }                                                                            \
    buf ^= 1;                                                                    \
  }

// 36 MFMAs: 2 tiles x 3 gen x (hh,hl,lh), kt-split accumulators (3-chains).
#define GEMM_COMBINE(TOUT)                                                       \
  {                                                                              \
    _Pragma("unroll")                                                            \
    for (int t2 = 0; t2 < 2; ++t2) {                                             \
      _Pragma("unroll")                                                          \
      for (int gen = 0; gen < 3; ++gen) {                                        \
        float q = (gen == 0) ? q0 : ((gen == 1) ? q1 : q2);                      \
        const int f0 = gen * 4 + t2 * 2;                                         \
        float4t ac0 = {0.f, 0.f, 0.f, 0.f};                                      \
        float4t ac1 = {0.f, 0.f, 0.f, 0.f};                                      \
        ac0 = __builtin_amdgcn_mfma_f32_16x16x32_f16(Ah[f0+0], Bh[0], ac0, 0, 0, 0); \
        ac1 = __builtin_amdgcn_mfma_f32_16x16x32_f16(Ah[f0+1], Bh[1], ac1, 0, 0, 0); \
        ac0 = __builtin_amdgcn_mfma_f32_16x16x32_f16(Ah[f0+0], Bl[0], ac0, 0, 0, 0); \
        ac1 = __builtin_amdgcn_mfma_f32_16x16x32_f16(Ah[f0+1], Bl[1], ac1, 0, 0, 0); \
        ac0 = __builtin_amdgcn_mfma_f32_16x16x32_f16(Al[f0+0], Bh[0], ac0, 0, 0, 0); \
        ac1 = __builtin_amdgcn_mfma_f32_16x16x32_f16(Al[f0+1], Bh[1], ac1, 0, 0, 0); \
        _Pragma("unroll")                                                        \
        for (int r4 = 0; r4 < 4; ++r4) {                                         \
          float sum = ac0[r4] + ac1[r4];                                         \
          if (gen == 0) TOUT[t2 * 4 + r4] = q * sum;                             \
          else          TOUT[t2 * 4 + r4] = fmaf(q, sum, TOUT[t2 * 4 + r4]);     \
        }                                                                        \
      }                                                                          \
    }                                                                            \
  }

__global__ __launch_bounds__(128)
__attribute__((amdgpu_waves_per_eu(1, 2)))
void liepe_mfma(
    const float* __restrict__ x,
    const float* __restrict__ r_grid,
    const float* __restrict__ L_param,
    float* __restrict__ out,
    int n_tokens)
{
    __shared__ __align__(16) unsigned stage[2][2][16][PSTR];  // 9.2KB

    const int lane = threadIdx.x & 63;
    const int w    = threadIdx.x >> 6;   // wave 0..1, owns m2 tiles {2w, 2w+1}
    const int c    = lane & 15;          // token column
    const int g    = lane >> 4;          // k-group / row sub-block

    int tok = blockIdx.x * 16 + c;
    if (tok >= n_tokens) tok = n_tokens - 1;

    // A-fragments for this wave's two row tiles, built INLINE from L:
    // element (lane, j) of tile (gen, t2, kt) =
    //   L'[16*(2w+t2) + (lane&15)][32kt + 8g + j],  L' = L - L^T.
    // 12 hi + 12 lo half8 (96 VGPRs). One-time, L2-resident.
    half8 Ah[12], Al[12];
    {
        #pragma unroll
        for (int t2 = 0; t2 < 2; ++t2) {
            const int i = 16 * (2 * w + t2) + (lane & 15);
            #pragma unroll
            for (int gen = 0; gen < 3; ++gen) {
                const float* Lg = L_param + gen * 4096;
                #pragma unroll
                for (int kt = 0; kt < 2; ++kt) {
                    const int kk0 = 32 * kt + 8 * g;
                    half8 hi, lo;
                    #pragma unroll
                    for (int j = 0; j < 8; ++j) {
                        int kk = kk0 + j;
                        float d = Lg[i * 64 + kk] - Lg[kk * 64 + i];
                        _Float16 h = (_Float16)d;
                        hi[j] = h;
                        lo[j] = (_Float16)(d - (float)h);
                    }
                    Ah[gen * 4 + t2 * 2 + kt] = hi;
                    Al[gen * 4 + t2 * 2 + kt] = lo;
                }
            }
        }
    }

    // x slices in D-layout: xv[4*t2+r4] = x[tok][16*(2w+t2) + 4g + r4].
    float xv[8];
    #pragma unroll
    for (int t2 = 0; t2 < 2; ++t2) {
        float4 v = *(const float4*)(x + tok * 64 + 16 * (2 * w + t2) + 4 * g);
        xv[4 * t2 + 0] = v.x; xv[4 * t2 + 1] = v.y;
        xv[4 * t2 + 2] = v.z; xv[4 * t2 + 3] = v.w;
    }

    // Per-token scalars — computed redundantly + identically in both waves.
    const float r0 = r_grid[tok * 3 + 0];
    const float r1 = r_grid[tok * 3 + 1];
    const float r2 = r_grid[tok * 3 + 2];
    const float sig2 = 0.5f * (r0 * r0 + r1 * r1 + r2 * r2);
    const float rho  = fmaf(17.3f, __builtin_sqrtf(sig2), 2.0f);
    const float inv_rho = 1.0f / rho;
    const int   M  = (int)rho + 12;     // tail ~1e-3 of scale, << f16-GEMM floor
    const int   ms = M + 10;
    const float q0 = r0 * inv_rho, q1 = r1 * inv_rho, q2 = r2 * inv_rho;

    // block max degree: wave-reduce suffices (every wave holds all 16 tokens).
    int maxM = M;
    #pragma unroll
    for (int off = 1; off < 64; off <<= 1)
        maxM = max(maxM, __shfl_xor(maxM, off));

    float jp = 0.f, jc = 0.f, N = 0.f;
    float b1[8] = {0.f, 0.f, 0.f, 0.f, 0.f, 0.f, 0.f, 0.f};
    float b2[8] = {0.f, 0.f, 0.f, 0.f, 0.f, 0.f, 0.f, 0.f};

    // ---- descent: Miller only (all b's exactly 0, no barriers needed) ----
    #pragma unroll 1
    for (int m = maxM + 10; m > maxM; --m) {
        bool sd = (m == ms);
        jc = sd ? 1e-12f : jc;
        jp = sd ? 0.f : jp;
        N  = sd ? (((m & 1) == 0) ? 2e-12f : 0.f) : N;
        float s = (jc > 1.0f) ? __builtin_amdgcn_rcpf(jc) : 1.0f;
        jc *= s; jp *= s; N *= s;
        float jm = fmaf((2.f * (float)m) * inv_rho, jc, -jp);
        jp = jc; jc = jm;
        int mm = m - 1;
        if ((mm & 1) == 0) N += (mm > 0) ? (jm + jm) : jm;
    }

    half8 Bh[2], Bl[2];
    int buf = 0;

    // ---- main fused Miller+Clenshaw loop (1 barrier per step, dbuf) ----
    #pragma unroll 1
    for (int m = maxM; m >= 1; --m) {
        bool sd = (m == ms);
        jc = sd ? 1e-12f : jc;
        jp = sd ? 0.f : jp;
        N  = sd ? (((m & 1) == 0) ? 2e-12f : 0.f) : N;

        // scale-invariant renorm: identical s in both waves (same jc chain)
        float s = (jc > 1.0f) ? __builtin_amdgcn_rcpf(jc) : 1.0f;
        jc *= s; jp *= s; N *= s;
        #pragma unroll
        for (int i = 0; i < 8; ++i) { b1[i] *= s; b2[i] *= s; }

        STAGE_AND_LOAD_B();

        float t[8];
        GEMM_COMBINE(t);

        float cf = (m <= M) ? (jc + jc) : 0.f;
        #pragma unroll
        for (int i = 0; i < 8; ++i) {
            float bn = fmaf(cf, xv[i], t[i] + b2[i]);
            b2[i] = b1[i];
            b1[i] = bn;
        }

        float jm = fmaf((2.f * (float)m) * inv_rho, jc, -jp);
        jp = jc; jc = jm;
        int mm = m - 1;
        if ((mm & 1) == 0) N += (mm > 0) ? (jm + jm) : jm;
    }

    // ---- final: b0 = J0*x + (2A/rho)b1 + b2;  y = (b0 - 0.5*(2A/rho)b1)/N ----
    {
        STAGE_AND_LOAD_B();
        float t[8];
        GEMM_COMBINE(t);
        #pragma unroll
        for (int t2 = 0; t2 < 2; ++t2) {
            float4 v;
            float y0 = fmaf(jc, xv[4*t2+0], t[4*t2+0] + b2[4*t2+0]);
            float y1 = fmaf(jc, xv[4*t2+1], t[4*t2+1] + b2[4*t2+1]);
            float y2 = fmaf(jc, xv[4*t2+2], t[4*t2+2] + b2[4*t2+2]);
            float y3 = fmaf(jc, xv[4*t2+3], t[4*t2+3] + b2[4*t2+3]);
            v.x = (y0 - 0.5f * t[4*t2+0]) / N;
            v.y = (y1 - 0.5f * t[4*t2+1]) / N;
            v.z = (y2 - 0.5f * t[4*t2+2]) / N;
            v.w = (y3 - 0.5f * t[4*t2+3]) / N;
            *(float4*)(out + tok * 64 + 16 * (2 * w + t2) + 4 * g) = v;
        }
    }
}

extern "C" void kernel_launch(void* const* d_in, const int* in_sizes, int n_in,
                              void* d_out, int out_size, void* d_ws, size_t ws_size,
                              hipStream_t stream) {
    const float* x = (const float*)d_in[0];
    const float* r = (const float*)d_in[1];
    const float* L = (const float*)d_in[2];
    // d_in[3] = P_sp: identity (allow_mixing=False) -> R_eff = R_r.
    float* out = (float*)d_out;

    int n_tokens = in_sizes[0] / 64;   // B*S = 8192

    int nwg = (n_tokens + 15) / 16;
    liepe_mfma<<<nwg, 128, 0, stream>>>(x, r, L, out, n_tokens);
}

// Round 17
// 29.935 us; speedup vs baseline: 1.2068x; 1.2068x over previous
//
#include <hip/hip_runtime.h>

// ExplicitLiePE via MFMA: y[b,s] = expm(A) @ x[b,s], A = sum_k r_k * 0.5*(L_k - L_k^T).
//
// FINAL structure (r15, best verified: 29.6us): 16-token groups, 4 waves/block
// row-split (wave w owns D-rows [16w,16w+16)), inline A-fragment build (no
// prep kernel), dbuf LDS b-exchange, 1 barrier/step, M margin +12,
// 512 blocks co-resident (2/CU, 2 waves/SIMD).
// Wall model (quantitatively verified r15): wall = maxM(~36) x ring(~1700cy);
// ring = issue + ds round-trip + barrier, dilated ~2x by SIMD sharing.
// Exhaustively closed neighbors (all regressed): r7/r8 column-duplication
// (46us), r9 fat blocks (37.7), r10 register-only no-exchange (47.5), r11
// conditional renorm (33.6), r12 double-step Z^2 (55.4), r14 MFMA de-chaining
// (37.7), r16 2-wave barrier-width (36.1 -- per-wave issue, not barrier
// convergence, is the binding term).
//
// Math: G_k = (L_k - L_k^T).B, t[:,c] = sum_k (r_k[c]/rho_c) G_k[:,c]
// via v_mfma_f32_16x16x32_f16 with f16 hi/lo split of both L' and b
// (Lhi.bhi + Lhi.blo + Llo.bhi; dropped term ~2^-24). Miller backward
// recurrence generates Bessel coeffs on the fly; per-step renorm
// s = jc>1 ? rcp(jc) : 1 (result scale-invariant). Seed at m==ms, gate m<=M.
//
// Layouts:
//  - C/D: reg r of lane l = D[16*w + (l>>4)*4 + r][l&15] (HW-verified m89/m91).
//  - A/B k-slot bijection k = 8*(l>>4)+j within each K=32 tile.
//  - staging: stage[buf][hi/lo][token c][dword]; token stride 36 dwords.

typedef _Float16 half8 __attribute__((ext_vector_type(8)));
typedef __fp16 fp16x2 __attribute__((ext_vector_type(2)));
typedef float float4t __attribute__((ext_vector_type(4)));

union H2U { fp16x2 h; unsigned u; };

__device__ __forceinline__ unsigned pkrtz2(float a, float b) {
    H2U v; v.h = __builtin_amdgcn_cvt_pkrtz(a, b); return v.u;
}
__device__ __forceinline__ float h2lo(unsigned u) { H2U v; v.u = u; return (float)v.h[0]; }
__device__ __forceinline__ float h2hi(unsigned u) { H2U v; v.u = u; return (float)v.h[1]; }

// ---------------- main kernel: 4 waves per block, 16 tokens per block --------

#define PSTR 36   // token stride in dwords (b128-aligned reads)

// stage own b1 slice (hi/lo f16), sync, load full-K B fragments, flip buffer.
#define STAGE_AND_LOAD_B()                                                       \
  {                                                                              \
    unsigned h0 = pkrtz2(b1[0], b1[1]);                                          \
    unsigned h1 = pkrtz2(b1[2], b1[3]);                                          \
    unsigned l0 = pkrtz2(b1[0] - h2lo(h0), b1[1] - h2hi(h0));                    \
    unsigned l1 = pkrtz2(b1[2] - h2lo(h1), b1[3] - h2hi(h1));                    \
    const int di = 8 * w + 2 * g;                                                \
    *(uint2*)&stage[buf][0][c][di] = make_uint2(h0, h1);                         \
    *(uint2*)&stage[buf][1][c][di] = make_uint2(l0, l1);                         \
    __syncthreads();                                                             \
    _Pragma("unroll")                                                            \
    for (int kt = 0; kt < 2; ++kt) {                                             \
      Bh[kt] = *(const half8*)&stage[buf][0][c][16 * kt + 4 * g];                \
      Bl[kt] = *(const half8*)&stage[buf][1][c][16 * kt + 4 * g];                \
    }                                                                            \
    buf ^= 1;                                                                    \
  }

// 18 MFMAs for this wave's 16-row tile; kt-split accumulators (6 short chains).
#define GEMM_COMBINE(TOUT)                                                       \
  {                                                                              \
    _Pragma("unroll")                                                            \
    for (int gen = 0; gen < 3; ++gen) {                                          \
      float q = (gen == 0) ? q0 : ((gen == 1) ? q1 : q2);                        \
      float4t ac0 = {0.f, 0.f, 0.f, 0.f};                                        \
      float4t ac1 = {0.f, 0.f, 0.f, 0.f};                                        \
      ac0 = __builtin_amdgcn_mfma_f32_16x16x32_f16(Ah[gen*2+0], Bh[0], ac0, 0, 0, 0); \
      ac1 = __builtin_amdgcn_mfma_f32_16x16x32_f16(Ah[gen*2+1], Bh[1], ac1, 0, 0, 0); \
      ac0 = __builtin_amdgcn_mfma_f32_16x16x32_f16(Ah[gen*2+0], Bl[0], ac0, 0, 0, 0); \
      ac1 = __builtin_amdgcn_mfma_f32_16x16x32_f16(Ah[gen*2+1], Bl[1], ac1, 0, 0, 0); \
      ac0 = __builtin_amdgcn_mfma_f32_16x16x32_f16(Al[gen*2+0], Bh[0], ac0, 0, 0, 0); \
      ac1 = __builtin_amdgcn_mfma_f32_16x16x32_f16(Al[gen*2+1], Bh[1], ac1, 0, 0, 0); \
      _Pragma("unroll")                                                          \
      for (int r4 = 0; r4 < 4; ++r4) {                                           \
        float sum = ac0[r4] + ac1[r4];                                           \
        if (gen == 0) TOUT[r4] = q * sum;                                        \
        else          TOUT[r4] = fmaf(q, sum, TOUT[r4]);                         \
      }                                                                          \
    }                                                                            \
  }

__global__ __launch_bounds__(256) void liepe_mfma(
    const float* __restrict__ x,
    const float* __restrict__ r_grid,
    const float* __restrict__ L_param,
    float* __restrict__ out,
    int n_tokens)
{
    __shared__ __align__(16) unsigned stage[2][2][16][PSTR];  // 18KB

    const int lane = threadIdx.x & 63;
    const int w    = threadIdx.x >> 6;   // row-slice / m2 tile, 0..3
    const int c    = lane & 15;          // token column
    const int g    = lane >> 4;          // k-group / row sub-block

    int tok = blockIdx.x * 16 + c;
    if (tok >= n_tokens) tok = n_tokens - 1;

    // A-fragments for this wave's row slice (m2 = w), built INLINE from L:
    // element (lane, j) of tile (gen, kt) = L'[16w + (lane&15)][32kt + 8g + j],
    // L' = L - L^T. 6 hi + 6 lo half8 (48 VGPRs). One-time, L2-resident.
    half8 Ah[6], Al[6];
    {
        const int i = 16 * w + (lane & 15);
        #pragma unroll
        for (int gen = 0; gen < 3; ++gen) {
            const float* Lg = L_param + gen * 4096;
            #pragma unroll
            for (int kt = 0; kt < 2; ++kt) {
                const int kk0 = 32 * kt + 8 * g;
                half8 hi, lo;
                #pragma unroll
                for (int j = 0; j < 8; ++j) {
                    int kk = kk0 + j;
                    float d = Lg[i * 64 + kk] - Lg[kk * 64 + i];
                    _Float16 h = (_Float16)d;
                    hi[j] = h;
                    lo[j] = (_Float16)(d - (float)h);
                }
                Ah[gen * 2 + kt] = hi;
                Al[gen * 2 + kt] = lo;
            }
        }
    }

    // x slice in D-layout: xv[r4] = x[tok][16w + 4g + r4].
    float xv[4];
    {
        float4 v = *(const float4*)(x + tok * 64 + 16 * w + 4 * g);
        xv[0] = v.x; xv[1] = v.y; xv[2] = v.z; xv[3] = v.w;
    }

    // Per-token scalars — computed redundantly + identically in all 4 waves.
    const float r0 = r_grid[tok * 3 + 0];
    const float r1 = r_grid[tok * 3 + 1];
    const float r2 = r_grid[tok * 3 + 2];
    const float sig2 = 0.5f * (r0 * r0 + r1 * r1 + r2 * r2);
    const float rho  = fmaf(17.3f, __builtin_sqrtf(sig2), 2.0f);
    const float inv_rho = 1.0f / rho;
    const int   M  = (int)rho + 12;     // tail ~1e-3 of scale, << f16-GEMM floor
    const int   ms = M + 10;
    const float q0 = r0 * inv_rho, q1 = r1 * inv_rho, q2 = r2 * inv_rho;

    // block max degree: wave-reduce suffices (every wave holds all 16 tokens).
    int maxM = M;
    #pragma unroll
    for (int off = 1; off < 64; off <<= 1)
        maxM = max(maxM, __shfl_xor(maxM, off));

    float jp = 0.f, jc = 0.f, N = 0.f;
    float b1[4] = {0.f, 0.f, 0.f, 0.f};
    float b2[4] = {0.f, 0.f, 0.f, 0.f};

    // ---- descent: Miller only (all b's exactly 0, no barriers needed) ----
    #pragma unroll 1
    for (int m = maxM + 10; m > maxM; --m) {
        bool sd = (m == ms);
        jc = sd ? 1e-12f : jc;
        jp = sd ? 0.f : jp;
        N  = sd ? (((m & 1) == 0) ? 2e-12f : 0.f) : N;
        float s = (jc > 1.0f) ? __builtin_amdgcn_rcpf(jc) : 1.0f;
        jc *= s; jp *= s; N *= s;
        float jm = fmaf((2.f * (float)m) * inv_rho, jc, -jp);
        jp = jc; jc = jm;
        int mm = m - 1;
        if ((mm & 1) == 0) N += (mm > 0) ? (jm + jm) : jm;
    }

    half8 Bh[2], Bl[2];
    int buf = 0;

    // ---- main fused Miller+Clenshaw loop (1 barrier per step, dbuf) ----
    #pragma unroll 1
    for (int m = maxM; m >= 1; --m) {
        bool sd = (m == ms);
        jc = sd ? 1e-12f : jc;
        jp = sd ? 0.f : jp;
        N  = sd ? (((m & 1) == 0) ? 2e-12f : 0.f) : N;

        // scale-invariant renorm: identical s in all 4 waves (same jc chain)
        float s = (jc > 1.0f) ? __builtin_amdgcn_rcpf(jc) : 1.0f;
        jc *= s; jp *= s; N *= s;
        #pragma unroll
        for (int i = 0; i < 4; ++i) { b1[i] *= s; b2[i] *= s; }

        STAGE_AND_LOAD_B();

        float t[4];
        GEMM_COMBINE(t);

        float cf = (m <= M) ? (jc + jc) : 0.f;
        #pragma unroll
        for (int i = 0; i < 4; ++i) {
            float bn = fmaf(cf, xv[i], t[i] + b2[i]);
            b2[i] = b1[i];
            b1[i] = bn;
        }

        float jm = fmaf((2.f * (float)m) * inv_rho, jc, -jp);
        jp = jc; jc = jm;
        int mm = m - 1;
        if ((mm & 1) == 0) N += (mm > 0) ? (jm + jm) : jm;
    }

    // ---- final: b0 = J0*x + (2A/rho)b1 + b2;  y = (b0 - 0.5*(2A/rho)b1)/N ----
    {
        STAGE_AND_LOAD_B();
        float t[4];
        GEMM_COMBINE(t);
        float4 v;
        float y0 = fmaf(jc, xv[0], t[0] + b2[0]);
        float y1 = fmaf(jc, xv[1], t[1] + b2[1]);
        float y2 = fmaf(jc, xv[2], t[2] + b2[2]);
        float y3 = fmaf(jc, xv[3], t[3] + b2[3]);
        v.x = (y0 - 0.5f * t[0]) / N;
        v.y = (y1 - 0.5f * t[1]) / N;
        v.z = (y2 - 0.5f * t[2]) / N;
        v.w = (y3 - 0.5f * t[3]) / N;
        *(float4*)(out + tok * 64 + 16 * w + 4 * g) = v;
    }
}

extern "C" void kernel_launch(void* const* d_in, const int* in_sizes, int n_in,
                              void* d_out, int out_size, void* d_ws, size_t ws_size,
                              hipStream_t stream) {
    const float* x = (const float*)d_in[0];
    const float* r = (const float*)d_in[1];
    const float* L = (const float*)d_in[2];
    // d_in[3] = P_sp: identity (allow_mixing=False) -> R_eff = R_r.
    float* out = (float*)d_out;

    int n_tokens = in_sizes[0] / 64;   // B*S = 8192

    int nwg = (n_tokens + 15) / 16;
    liepe_mfma<<<nwg, 256, 0, stream>>>(x, r, L, out, n_tokens);
}